// Round 1
// baseline (1095.019 us; speedup 1.0000x reference)
//
#include <hip/hip_runtime.h>
#include <math.h>

#define N_NODE 100000
#define DEPTH  10
#define N_EDGE 1600000
#define D_FEAT 32
#define D_OUT  ((DEPTH + 1) * D_FEAT)   // 352 floats per node in output

// ---------------------------------------------------------------------------
// Phase 1: degree count (in-degree over `row`), matching
//          deg = segment_sum(ones_like(edge_attr), row)
// ---------------------------------------------------------------------------
__global__ void count_kernel(const int* __restrict__ row, int* __restrict__ cnt, int E) {
    int e = blockIdx.x * blockDim.x + threadIdx.x;
    if (e < E) atomicAdd(&cnt[row[e]], 1);
}

// ---------------------------------------------------------------------------
// Phase 2: single-block exclusive scan over cnt -> rowStart (N+1 entries)
// 1024 threads, shfl-based wave scans, ~3 barriers per 1024-chunk.
// ---------------------------------------------------------------------------
__device__ inline int wave_incl_scan(int v) {
    int lane = threadIdx.x & 63;
    #pragma unroll
    for (int off = 1; off < 64; off <<= 1) {
        int t = __shfl_up(v, off, 64);
        if (lane >= off) v += t;
    }
    return v;
}

__global__ void scan_kernel(const int* __restrict__ cnt, int* __restrict__ rowStart, int n) {
    __shared__ int partials[16];
    __shared__ int carry_s;
    if (threadIdx.x == 0) carry_s = 0;
    __syncthreads();

    for (int base = 0; base < n; base += 1024) {
        int i = base + (int)threadIdx.x;
        int v = (i < n) ? cnt[i] : 0;
        int incl = wave_incl_scan(v);
        int wid  = threadIdx.x >> 6;
        int lane = threadIdx.x & 63;
        if (lane == 63) partials[wid] = incl;
        __syncthreads();
        if (wid == 0) {
            int p = (lane < 16) ? partials[lane] : 0;
            #pragma unroll
            for (int off = 1; off < 16; off <<= 1) {
                int t = __shfl_up(p, off, 64);
                if (lane >= off) p += t;
            }
            if (lane < 16) partials[lane] = p;  // inclusive scan of wave totals
        }
        __syncthreads();
        int wave_off = (wid > 0) ? partials[wid - 1] : 0;
        if (i < n) rowStart[i] = carry_s + wave_off + incl - v;  // exclusive
        __syncthreads();
        if (threadIdx.x == 1023) carry_s += partials[15];        // chunk total
        __syncthreads();
    }
    if (threadIdx.x == 0) rowStart[n] = carry_s;
}

// ---------------------------------------------------------------------------
// Phase 3: dinv = (deg<0.5 ? deg+1 : deg)^-0.5
// ---------------------------------------------------------------------------
__global__ void dinv_kernel(const int* __restrict__ cnt, float* __restrict__ dinv, int n) {
    int i = blockIdx.x * blockDim.x + threadIdx.x;
    if (i < n) {
        float d = (float)cnt[i];
        if (d < 0.5f) d += 1.0f;
        dinv[i] = 1.0f / sqrtf(d);
    }
}

// ---------------------------------------------------------------------------
// Phase 4: scatter edges to CSR, val = dinv[row] * edge_attr * dinv[col]
// ---------------------------------------------------------------------------
__global__ void scatter_kernel(const int* __restrict__ row, const int* __restrict__ col,
                               const float* __restrict__ eattr,
                               const int* __restrict__ rowStart, int* __restrict__ fill,
                               const float* __restrict__ dinv,
                               int* __restrict__ csr_col, float* __restrict__ csr_val, int E) {
    int e = blockIdx.x * blockDim.x + threadIdx.x;
    if (e < E) {
        int r = row[e], c = col[e];
        int p = rowStart[r] + atomicAdd(&fill[r], 1);
        csr_col[p] = c;
        csr_val[p] = dinv[r] * eattr[e] * dinv[c];
    }
}

// ---------------------------------------------------------------------------
// alphas_t[L] = BASE_ALPHA * tanh(alphas[L]), BASE_ALPHA = 1
// ---------------------------------------------------------------------------
__global__ void alpha_kernel(const float* __restrict__ alphas, float* __restrict__ alphaT) {
    int i = threadIdx.x;
    if (i <= DEPTH) alphaT[i] = tanhf(alphas[i]);
}

// ---------------------------------------------------------------------------
// x_0 = x  -> out[node, 0, :]
// ---------------------------------------------------------------------------
__global__ void copyx_kernel(const float* __restrict__ x, float* __restrict__ out) {
    int i = blockIdx.x * blockDim.x + threadIdx.x;  // over N_NODE * 32
    if (i < N_NODE * D_FEAT) {
        int node = i >> 5, f = i & 31;
        out[node * D_OUT + f] = x[i];
    }
}

// ---------------------------------------------------------------------------
// Phase 5 (x10): SpMM level L. 32 lanes per row (lane = feat), 8 rows/block.
// out[node, L, :] = alphaT[L] * sum_e val[e] * out[col[e], L-1, :]
// ---------------------------------------------------------------------------
__global__ __launch_bounds__(256) void spmm_kernel(const int* __restrict__ rowStart,
                                                   const int* __restrict__ csr_col,
                                                   const float* __restrict__ csr_val,
                                                   const float* __restrict__ alphaT,
                                                   int L, float* __restrict__ out) {
    int gid  = (blockIdx.x * blockDim.x + threadIdx.x) >> 5;  // row id
    int feat = threadIdx.x & 31;
    if (gid >= N_NODE) return;

    int start = rowStart[gid];
    int end   = rowStart[gid + 1];
    int prev_off = (L - 1) * D_FEAT + feat;

    float acc = 0.0f;
    for (int e = start; e < end; ++e) {
        int   c = csr_col[e];
        float v = csr_val[e];
        acc += v * out[c * D_OUT + prev_off];
    }
    out[gid * D_OUT + L * D_FEAT + feat] = alphaT[L] * acc;
}

// ---------------------------------------------------------------------------
extern "C" void kernel_launch(void* const* d_in, const int* in_sizes, int n_in,
                              void* d_out, int out_size, void* d_ws, size_t ws_size,
                              hipStream_t stream) {
    const float* x      = (const float*)d_in[0];
    const int*   eidx   = (const int*)d_in[1];     // (2, E): row = [0,E), col = [E,2E)
    const float* eattr  = (const float*)d_in[2];
    const float* alphas = (const float*)d_in[3];
    float* out = (float*)d_out;

    const int* row = eidx;
    const int* col = eidx + N_EDGE;

    // ---- workspace partition (256B aligned) ----
    char* p = (char*)d_ws;
    auto alloc = [&](size_t bytes) { char* r = p; p += (bytes + 255) & ~(size_t)255; return (void*)r; };
    int*   cnt      = (int*)  alloc((size_t)N_NODE * 4);
    int*   rowStart = (int*)  alloc((size_t)(N_NODE + 1) * 4);
    int*   fill     = (int*)  alloc((size_t)N_NODE * 4);
    float* dinv     = (float*)alloc((size_t)N_NODE * 4);
    float* alphaT   = (float*)alloc(64);
    int*   csr_col  = (int*)  alloc((size_t)N_EDGE * 4);
    float* csr_val  = (float*)alloc((size_t)N_EDGE * 4);
    (void)ws_size; (void)in_sizes; (void)n_in; (void)out_size;

    hipMemsetAsync(cnt,  0, (size_t)N_NODE * 4, stream);
    hipMemsetAsync(fill, 0, (size_t)N_NODE * 4, stream);

    const int TB = 256;
    int eBlocks = (N_EDGE + TB - 1) / TB;
    int nBlocks = (N_NODE + TB - 1) / TB;

    count_kernel<<<eBlocks, TB, 0, stream>>>(row, cnt, N_EDGE);
    scan_kernel<<<1, 1024, 0, stream>>>(cnt, rowStart, N_NODE);
    dinv_kernel<<<nBlocks, TB, 0, stream>>>(cnt, dinv, N_NODE);
    scatter_kernel<<<eBlocks, TB, 0, stream>>>(row, col, eattr, rowStart, fill, dinv,
                                               csr_col, csr_val, N_EDGE);
    alpha_kernel<<<1, 64, 0, stream>>>(alphas, alphaT);
    copyx_kernel<<<(N_NODE * D_FEAT + TB - 1) / TB, TB, 0, stream>>>(x, out);

    int spmmBlocks = (N_NODE * 32 + TB - 1) / TB;  // 32 lanes per row
    for (int L = 1; L <= DEPTH; ++L) {
        spmm_kernel<<<spmmBlocks, TB, 0, stream>>>(rowStart, csr_col, csr_val, alphaT, L, out);
    }
}

// Round 2
// 543.208 us; speedup vs baseline: 2.0158x; 2.0158x over previous
//
#include <hip/hip_runtime.h>
#include <math.h>

#define N_NODE 100000
#define DEPTH  10
#define N_EDGE 1600000
#define D_FEAT 32
#define D_OUT  ((DEPTH + 1) * D_FEAT)   // 352 floats per node in output
#define NB_SCAN ((N_NODE + 255) / 256)  // 391 scan blocks

// ---------------------------------------------------------------------------
// Phase 1: degree count (in-degree over `row`)
// ---------------------------------------------------------------------------
__global__ void count_kernel(const int* __restrict__ row, int* __restrict__ cnt, int E) {
    int e = blockIdx.x * blockDim.x + threadIdx.x;
    if (e < E) atomicAdd(&cnt[row[e]], 1);
}

// ---------------------------------------------------------------------------
// Phase 2: hierarchical exclusive scan (3 kernels)
// ---------------------------------------------------------------------------
__device__ inline int wave_incl_scan(int v) {
    int lane = threadIdx.x & 63;
    #pragma unroll
    for (int off = 1; off < 64; off <<= 1) {
        int t = __shfl_up(v, off, 64);
        if (lane >= off) v += t;
    }
    return v;
}

// 2a: per-block (256 elems) exclusive scan + block totals
__global__ void blockscan_kernel(const int* __restrict__ cnt, int* __restrict__ rowStart,
                                 int* __restrict__ blockSums, int n) {
    __shared__ int partials[4];
    int i = blockIdx.x * 256 + threadIdx.x;
    int v = (i < n) ? cnt[i] : 0;
    int incl = wave_incl_scan(v);
    int wid = threadIdx.x >> 6, lane = threadIdx.x & 63;
    if (lane == 63) partials[wid] = incl;
    __syncthreads();
    int woff = 0;
    #pragma unroll
    for (int w = 0; w < 4; ++w) woff += (w < wid) ? partials[w] : 0;
    if (i < n) rowStart[i] = woff + incl - v;               // block-local exclusive
    if (threadIdx.x == 255) blockSums[blockIdx.x] = woff + incl;
}

// 2b: single block scans the (<=512) block sums in place (exclusive); [nb] = total
__global__ void scansums_kernel(int* __restrict__ blockSums, int nb) {
    __shared__ int partials[8];
    int i = threadIdx.x;                                    // 512 threads
    int v = (i < nb) ? blockSums[i] : 0;
    int incl = wave_incl_scan(v);
    int wid = i >> 6, lane = i & 63;
    if (lane == 63) partials[wid] = incl;
    __syncthreads();
    int woff = 0;
    #pragma unroll
    for (int w = 0; w < 8; ++w) woff += (w < wid) ? partials[w] : 0;
    if (i < nb) blockSums[i] = woff + incl - v;             // exclusive
    if (i == 511) blockSums[nb] = woff + incl;              // grand total
}

// 2c: add block offsets; rowStart[n] = total
__global__ void addoffs_kernel(int* __restrict__ rowStart, const int* __restrict__ blockSums,
                               int n, int nb) {
    int i = blockIdx.x * 256 + threadIdx.x;
    if (i < n)  rowStart[i] += blockSums[i >> 8];
    if (i == n) rowStart[n] = blockSums[nb];
}

// ---------------------------------------------------------------------------
// Phase 3: dinv = (deg<0.5 ? deg+1 : deg)^-0.5
// ---------------------------------------------------------------------------
__global__ void dinv_kernel(const int* __restrict__ cnt, float* __restrict__ dinv, int n) {
    int i = blockIdx.x * blockDim.x + threadIdx.x;
    if (i < n) {
        float d = (float)cnt[i];
        if (d < 0.5f) d += 1.0f;
        dinv[i] = 1.0f / sqrtf(d);
    }
}

// ---------------------------------------------------------------------------
// Phase 4: scatter edges to CSR as combined 8B {col, val} entries.
// Consumes cnt via atomicSub (positions filled back-to-front; order arbitrary).
// ---------------------------------------------------------------------------
__global__ void scatter_kernel(const int* __restrict__ row, const int* __restrict__ col,
                               const float* __restrict__ eattr,
                               const int* __restrict__ rowStart, int* __restrict__ cnt,
                               const float* __restrict__ dinv,
                               int2* __restrict__ csr, int E) {
    int e = blockIdx.x * blockDim.x + threadIdx.x;
    if (e < E) {
        int r = row[e], c = col[e];
        int p = rowStart[r] + atomicSub(&cnt[r], 1) - 1;
        float val = dinv[r] * eattr[e] * dinv[c];
        csr[p] = make_int2(c, __float_as_int(val));
    }
}

// ---------------------------------------------------------------------------
// alphas_t[L] = tanh(alphas[L]) (BASE_ALPHA = 1)
// ---------------------------------------------------------------------------
__global__ void alpha_kernel(const float* __restrict__ alphas, float* __restrict__ alphaT) {
    int i = threadIdx.x;
    if (i <= DEPTH) alphaT[i] = tanhf(alphas[i]);
}

// ---------------------------------------------------------------------------
// x_0 = x -> out[node, 0, :], float4 copy
// ---------------------------------------------------------------------------
__global__ void copyx_kernel(const float4* __restrict__ x4, float4* __restrict__ out4) {
    int i = blockIdx.x * blockDim.x + threadIdx.x;  // over N_NODE * 8
    if (i < N_NODE * 8) {
        int node = i >> 3, q = i & 7;
        out4[(size_t)node * 88 + q] = x4[i];
    }
}

// ---------------------------------------------------------------------------
// Phase 5 (x10): SpMM level L. ONE WAVE PER ROW.
// lane = (s,q): s = edge slot (0..7), q = feat quad (0..7).
// Per iteration: 8 edges gathered concurrently, each as 8 lanes x float4.
// Cross-slot shfl_xor reduction at the end; lanes s==0 store the row.
// ---------------------------------------------------------------------------
__global__ __launch_bounds__(256) void spmm_kernel(const int* __restrict__ rowStart,
                                                   const int2* __restrict__ csr,
                                                   const float* __restrict__ alphaT,
                                                   int L, float* __restrict__ out) {
    int rowid = (int)((blockIdx.x * 256 + threadIdx.x) >> 6);
    if (rowid >= N_NODE) return;
    int lane = threadIdx.x & 63;
    int s = lane >> 3;                 // edge slot
    int q = lane & 7;                  // feat quad

    int start = rowStart[rowid];
    int end   = rowStart[rowid + 1];

    const float4* __restrict__ out4 = (const float4*)out;
    int prev = (L - 1) * 8 + q;

    float4 acc = make_float4(0.f, 0.f, 0.f, 0.f);
    for (int e = start + s; e < end; e += 8) {
        int2  cv = csr[e];
        float v  = __int_as_float(cv.y);
        float4 h = out4[(size_t)cv.x * 88 + prev];
        acc.x += v * h.x; acc.y += v * h.y; acc.z += v * h.z; acc.w += v * h.w;
    }

    // reduce across the 8 edge slots (lane-xor 8,16,32)
    #pragma unroll
    for (int m = 8; m < 64; m <<= 1) {
        acc.x += __shfl_xor(acc.x, m, 64);
        acc.y += __shfl_xor(acc.y, m, 64);
        acc.z += __shfl_xor(acc.z, m, 64);
        acc.w += __shfl_xor(acc.w, m, 64);
    }

    if (s == 0) {
        float a = alphaT[L];
        float4 r = make_float4(a * acc.x, a * acc.y, a * acc.z, a * acc.w);
        ((float4*)out)[(size_t)rowid * 88 + L * 8 + q] = r;
    }
}

// ---------------------------------------------------------------------------
extern "C" void kernel_launch(void* const* d_in, const int* in_sizes, int n_in,
                              void* d_out, int out_size, void* d_ws, size_t ws_size,
                              hipStream_t stream) {
    const float* x      = (const float*)d_in[0];
    const int*   eidx   = (const int*)d_in[1];     // (2, E): row = [0,E), col = [E,2E)
    const float* eattr  = (const float*)d_in[2];
    const float* alphas = (const float*)d_in[3];
    float* out = (float*)d_out;

    const int* row = eidx;
    const int* col = eidx + N_EDGE;

    // ---- workspace partition (256B aligned) ----
    char* p = (char*)d_ws;
    auto alloc = [&](size_t bytes) { char* r = p; p += (bytes + 255) & ~(size_t)255; return (void*)r; };
    int*   cnt       = (int*)  alloc((size_t)N_NODE * 4);
    int*   rowStart  = (int*)  alloc((size_t)(N_NODE + 1) * 4);
    int*   blockSums = (int*)  alloc((size_t)(NB_SCAN + 1) * 4);
    float* dinv      = (float*)alloc((size_t)N_NODE * 4);
    float* alphaT    = (float*)alloc(64);
    int2*  csr       = (int2*) alloc((size_t)N_EDGE * 8);
    (void)ws_size; (void)in_sizes; (void)n_in; (void)out_size;

    hipMemsetAsync(cnt, 0, (size_t)N_NODE * 4, stream);

    const int TB = 256;
    int eBlocks = (N_EDGE + TB - 1) / TB;
    int nBlocks = (N_NODE + TB - 1) / TB;

    count_kernel<<<eBlocks, TB, 0, stream>>>(row, cnt, N_EDGE);
    blockscan_kernel<<<NB_SCAN, TB, 0, stream>>>(cnt, rowStart, blockSums, N_NODE);
    scansums_kernel<<<1, 512, 0, stream>>>(blockSums, NB_SCAN);
    addoffs_kernel<<<(N_NODE + 1 + TB - 1) / TB, TB, 0, stream>>>(rowStart, blockSums, N_NODE, NB_SCAN);
    dinv_kernel<<<nBlocks, TB, 0, stream>>>(cnt, dinv, N_NODE);
    scatter_kernel<<<eBlocks, TB, 0, stream>>>(row, col, eattr, rowStart, cnt, dinv, csr, N_EDGE);
    alpha_kernel<<<1, 64, 0, stream>>>(alphas, alphaT);
    copyx_kernel<<<(N_NODE * 8 + TB - 1) / TB, TB, 0, stream>>>((const float4*)x, (float4*)out);

    int spmmBlocks = (N_NODE * 64 + TB - 1) / TB;  // one 64-lane wave per row
    for (int L = 1; L <= DEPTH; ++L) {
        spmm_kernel<<<spmmBlocks, TB, 0, stream>>>(rowStart, csr, alphaT, L, out);
    }
}